// Round 1
// baseline (11476.500 us; speedup 1.0000x reference)
//
#include <hip/hip_runtime.h>
#include <math.h>

// Problem dims
#define BSZ   128
#define TLEN  256
#define NCLS  128
#define WDIM  512
#define XDIM  640       // NC + WD
#define G4    2048      // 4*UNITS

// Geometry: 8 batch-groups x 32 j-tiles = 256 blocks, 256 threads
#define BT    16        // batch rows per group
#define JTS   16        // h columns per block
#define NBLK  256
#define NTHR  256

// ws layout (float offsets)
#define H_OFF    0                    // 2 * 128 * 512 h double buffer
#define LOG_OFF  131072               // 3 * 128 * 128 logits triple buffer
#define W0_OFF   180224               // 2048: bias + 1e-5*colsum(W[640:768])
#define CTR_OFF  182272               // 8 barrier counters, stride 16 (64B lines)
#define WS_FLOATS (CTR_OFF + 128)

__device__ __forceinline__ float sigmoidf_(float x) {
  return 1.0f / (1.0f + expf(-x));
}

__global__ void setup_kernel(const float* __restrict__ W,
                             const float* __restrict__ bias,
                             float* __restrict__ ws) {
  int tid = blockIdx.x * blockDim.x + threadIdx.x;   // 64*256 = 16384 threads
  for (int i = tid; i < 3 * BSZ * NCLS; i += 64 * 256)
    ws[LOG_OFF + i] = 0.0f;
  if (tid < 8 * 16)
    ((unsigned int*)(ws + CTR_OFF))[tid] = 0u;
  if (tid < G4) {
    float s = 0.0f;
    #pragma unroll 4
    for (int r = 0; r < NCLS; ++r)
      s += W[(size_t)(XDIM + r) * G4 + tid];
    ws[W0_OFF + tid] = bias[tid] + 1e-5f * s;
  }
}

__global__ void __launch_bounds__(NTHR, 1)
lstm_main(const float* __restrict__ xc, const float* __restrict__ xw,
          const float* __restrict__ W,  const float* __restrict__ U,
          const float* __restrict__ bias, const float* __restrict__ Wsm,
          const float* __restrict__ bsv, int* __restrict__ out,
          float* __restrict__ ws)
{
  __shared__ float U_lds[512 * 64];    // 128 KB: resident U tile [k][cc]
  __shared__ float ins_lds[BT * 132];  // staging chunk [b][128], padded
  __shared__ float z_lds[BT * 68];     // z exchange [b][64 gate-cols], padded
  __shared__ float hl_lds[BT * 17];    // h_new tile [b][16], padded
  __shared__ float red_v[NTHR];
  __shared__ int   red_i[NTHR];
  __shared__ int   idx_lds[BT];

  const int tid = threadIdx.x;
  const int blk = blockIdx.x;
  // XCD-aware swizzle (assume XCD = blk%8): same-XCD blocks share 4 j-tiles
  const int x8 = blk & 7;
  const int q  = blk >> 3;
  const int jt = x8 * 4 + (q & 3);     // 0..31
  const int bg = q >> 2;               // 0..7
  const int b0 = bg * BT;
  const int j0 = jt * JTS;

  // GEMM mapping: thread = (batch row gb, gate gg, 4-col group j4)
  const int gb  = tid & 15;
  const int qq  = tid >> 4;
  const int gg  = qq & 3;
  const int j4  = qq >> 2;
  const int c0  = gg * 512 + j0 + j4 * 4;   // global column in [0,2048)
  const int cc0 = gg * 16 + j4 * 4;         // LDS column in [0,64)

  // update/stage/argmax mapping: thread = (row ub, slot uj)
  const int ub = tid >> 4;
  const int uj = tid & 15;

  float* hbuf   = ws + H_OFF;
  float* logits = ws + LOG_OFF;
  unsigned int* ctr = (unsigned int*)(ws + CTR_OFF) + bg * 16;

  // Load resident U tile: U_lds[k*64 + cc] = U[k][col(cc)]
  {
    int cc  = tid & 63;
    int col = (cc >> 4) * 512 + j0 + (cc & 15);
    int k0  = tid >> 6;  // 0..3
    for (int kk = 0; kk < 128; ++kk) {
      int k = k0 + kk * 4;
      U_lds[k * 64 + cc] = U[(size_t)k * G4 + col];
    }
  }

  // x-feature projection (depth 640) for step tt — no recurrent deps
  auto x_part = [&](int tt) {
    float4 a4 = make_float4(0.f, 0.f, 0.f, 0.f);
    #pragma unroll 1
    for (int ch = 0; ch < 5; ++ch) {
      const float* src = (ch == 0)
        ? (xc + ((size_t)(b0 + ub) * TLEN + tt) * NCLS + uj * 8)
        : (xw + ((size_t)(b0 + ub) * TLEN + tt) * WDIM + (ch - 1) * 128 + uj * 8);
      float4 v0 = *(const float4*)(src);
      float4 v1 = *(const float4*)(src + 4);
      __syncthreads();
      *(float4*)(ins_lds + ub * 132 + uj * 8)     = v0;
      *(float4*)(ins_lds + ub * 132 + uj * 8 + 4) = v1;
      __syncthreads();
      const float* wp = W + (size_t)(ch * 128) * G4 + c0;
      const float* ip = ins_lds + gb * 132;
      #pragma unroll 8
      for (int kk = 0; kk < 128; ++kk) {
        float a = ip[kk];
        float4 w4 = *(const float4*)(wp + (size_t)kk * G4);
        a4.x = fmaf(a, w4.x, a4.x);
        a4.y = fmaf(a, w4.y, a4.y);
        a4.z = fmaf(a, w4.z, a4.z);
        a4.w = fmaf(a, w4.w, a4.w);
      }
    }
    return a4;
  };

  float creg = 0.0f;      // cell state: thread owns (b0+ub, j0+uj) forever
  __syncthreads();
  float4 xacc = x_part(0);

  for (int t = 0; t < TLEN; ++t) {
    float4 acc = xacc;

    if (t == 0) {
      const float4 w0 = *(const float4*)(ws + W0_OFF + c0);
      acc.x += w0.x; acc.y += w0.y; acc.z += w0.z; acc.w += w0.w;
    } else {
      // ---- argmax of step t-1 logits (redundant per block) + buffer rotation
      {
        const float* lsrc = logits + ((t + 2) % 3) * (BSZ * NCLS)
                          + (b0 + ub) * NCLS + uj * 8;
        float bv = -1e30f; int bi = 0;
        #pragma unroll
        for (int r = 0; r < 8; ++r) {
          float v = lsrc[r] + bsv[uj * 8 + r];
          if (v > bv) { bv = v; bi = uj * 8 + r; }
        }
        red_v[tid] = bv; red_i[tid] = bi;
        // zero buf[(t+1)%3] group rows (last read at step t-1, behind barrier)
        float* lz = logits + ((t + 1) % 3) * (BSZ * NCLS) + b0 * NCLS;
        if (tid < 64) lz[jt * 64 + tid] = 0.0f;
        __syncthreads();
        if (uj == 0) {
          float v = red_v[tid]; int vi = red_i[tid];
          #pragma unroll
          for (int s = 1; s < 16; ++s) {      // first-max tie-break: strict >
            float v2 = red_v[tid + s];
            if (v2 > v) { v = v2; vi = red_i[tid + s]; }
          }
          idx_lds[ub] = vi;
          if (jt == 0) out[(b0 + ub) * TLEN + (t - 1)] = vi;
        }
        __syncthreads();
      }
      // ---- bias + one-hot word row of W
      {
        int wr = XDIM + idx_lds[gb];
        const float4 b4 = *(const float4*)(bias + c0);
        const float4 w4 = *(const float4*)(W + (size_t)wr * G4 + c0);
        acc.x += b4.x + w4.x;  acc.y += b4.y + w4.y;
        acc.z += b4.z + w4.z;  acc.w += b4.w + w4.w;
      }
      // ---- h @ U from LDS-resident tile
      const float* hprev = hbuf + ((t + 1) & 1) * (BSZ * 512);
      #pragma unroll 1
      for (int ch = 0; ch < 4; ++ch) {
        const float* hsrc = hprev + (size_t)(b0 + ub) * 512 + ch * 128 + uj * 8;
        float4 v0 = *(const float4*)(hsrc);
        float4 v1 = *(const float4*)(hsrc + 4);
        __syncthreads();
        *(float4*)(ins_lds + ub * 132 + uj * 8)     = v0;
        *(float4*)(ins_lds + ub * 132 + uj * 8 + 4) = v1;
        __syncthreads();
        const float* up = U_lds + (ch * 128) * 64 + cc0;
        const float* ip = ins_lds + gb * 132;
        #pragma unroll 8
        for (int kk = 0; kk < 128; ++kk) {
          float a = ip[kk];
          float4 u4 = *(const float4*)(up + kk * 64);
          acc.x = fmaf(a, u4.x, acc.x);
          acc.y = fmaf(a, u4.y, acc.y);
          acc.z = fmaf(a, u4.z, acc.z);
          acc.w = fmaf(a, u4.w, acc.w);
        }
      }
    }

    // ---- z exchange: regroup 4 gates per (b,j)
    *(float4*)(z_lds + gb * 68 + cc0) = acc;
    __syncthreads();

    // ---- gate nonlinearities + cell/hidden update
    {
      float zi = z_lds[ub * 68 +  0 + uj];
      float zf = z_lds[ub * 68 + 16 + uj];
      float zg = z_lds[ub * 68 + 32 + uj];
      float zo = z_lds[ub * 68 + 48 + uj];
      float iv = sigmoidf_(zi);
      float fv = sigmoidf_(zf);
      float gv = tanhf(zg);
      float ov = sigmoidf_(zo);
      creg = fv * creg + iv * gv;
      float hn = ov * tanhf(creg);
      hbuf[(t & 1) * (BSZ * 512) + (size_t)(b0 + ub) * 512 + j0 + uj] = hn;
      hl_lds[ub * 17 + uj] = hn;
    }
    __syncthreads();

    // ---- logits partial over this block's 16 j, atomic into buf[t%3]
    {
      const int m0 = uj * 8;
      float p0=0,p1=0,p2=0,p3=0,p4=0,p5=0,p6=0,p7=0;
      #pragma unroll
      for (int j = 0; j < 16; ++j) {
        float hv = hl_lds[ub * 17 + j];
        const float4 wa = *(const float4*)(Wsm + (size_t)(j0 + j) * NCLS + m0);
        const float4 wb = *(const float4*)(Wsm + (size_t)(j0 + j) * NCLS + m0 + 4);
        p0 = fmaf(hv, wa.x, p0); p1 = fmaf(hv, wa.y, p1);
        p2 = fmaf(hv, wa.z, p2); p3 = fmaf(hv, wa.w, p3);
        p4 = fmaf(hv, wb.x, p4); p5 = fmaf(hv, wb.y, p5);
        p6 = fmaf(hv, wb.z, p6); p7 = fmaf(hv, wb.w, p7);
      }
      float* ld = logits + (t % 3) * (BSZ * NCLS) + (size_t)(b0 + ub) * NCLS + m0;
      atomicAdd(ld + 0, p0); atomicAdd(ld + 1, p1);
      atomicAdd(ld + 2, p2); atomicAdd(ld + 3, p3);
      atomicAdd(ld + 4, p4); atomicAdd(ld + 5, p5);
      atomicAdd(ld + 6, p6); atomicAdd(ld + 7, p7);
    }

    // ---- group barrier: arrive, overlap next x-projection, then wait
    __syncthreads();
    if (tid == 0) {
      __threadfence();
      __hip_atomic_fetch_add(ctr, 1u, __ATOMIC_RELEASE, __HIP_MEMORY_SCOPE_AGENT);
    }
    if (t + 1 < TLEN) xacc = x_part(t + 1);   // hides barrier latency
    if (tid == 0) {
      const unsigned int tgt = 32u * (unsigned)(t + 1);
      while (__hip_atomic_load(ctr, __ATOMIC_ACQUIRE, __HIP_MEMORY_SCOPE_AGENT) < tgt)
        __builtin_amdgcn_s_sleep(1);
    }
    __syncthreads();
  }

  // ---- epilogue: argmax for final step (buf (TLEN-1)%3 == 0)
  if (jt == 0) {
    const float* lsrc = logits + ((TLEN - 1) % 3) * (BSZ * NCLS)
                      + (b0 + ub) * NCLS + uj * 8;
    float bv = -1e30f; int bi = 0;
    #pragma unroll
    for (int r = 0; r < 8; ++r) {
      float v = lsrc[r] + bsv[uj * 8 + r];
      if (v > bv) { bv = v; bi = uj * 8 + r; }
    }
    red_v[tid] = bv; red_i[tid] = bi;
    __syncthreads();
    if (uj == 0) {
      float v = red_v[tid]; int vi = red_i[tid];
      #pragma unroll
      for (int s = 1; s < 16; ++s) {
        float v2 = red_v[tid + s];
        if (v2 > v) { v = v2; vi = red_i[tid + s]; }
      }
      out[(b0 + ub) * TLEN + (TLEN - 1)] = vi;
    }
  }
}

extern "C" void kernel_launch(void* const* d_in, const int* in_sizes, int n_in,
                              void* d_out, int out_size, void* d_ws, size_t ws_size,
                              hipStream_t stream) {
  (void)in_sizes; (void)n_in; (void)out_size; (void)ws_size;
  const float* xc  = (const float*)d_in[0];
  const float* xw  = (const float*)d_in[1];
  const float* W   = (const float*)d_in[2];
  const float* U   = (const float*)d_in[3];
  const float* b   = (const float*)d_in[4];
  const float* Wsm = (const float*)d_in[5];
  const float* bs  = (const float*)d_in[6];
  int*   out = (int*)d_out;
  float* ws  = (float*)d_ws;

  hipLaunchKernelGGL(setup_kernel, dim3(64), dim3(256), 0, stream, W, b, ws);

  void* args[] = { (void*)&xc, (void*)&xw, (void*)&W, (void*)&U, (void*)&b,
                   (void*)&Wsm, (void*)&bs, (void*)&out, (void*)&ws };
  hipLaunchCooperativeKernel((const void*)lstm_main, dim3(NBLK), dim3(NTHR),
                             args, 0, stream);
}

// Round 2
// 10917.933 us; speedup vs baseline: 1.0512x; 1.0512x over previous
//
#include <hip/hip_runtime.h>
#include <math.h>

// Problem dims
#define BSZ   128
#define TLEN  256
#define NCLS  128
#define WDIM  512
#define XDIM  640       // NC + WD
#define G4    2048      // 4*UNITS

// Geometry: 8 batch-groups (XCD-local) x 32 j-tiles = 256 blocks, 512 threads
#define BT    16        // batch rows per group
#define JTS   16        // h columns per block
#define NBLK  256
#define NTHR  512

// ws layout (float offsets)
#define H_OFF    0                    // 2 * 128 * 512 h double buffer
#define LOG_OFF  131072               // 3 * 128 * 128 logits triple buffer
#define W0_OFF   180224               // 2048: bias + 1e-5*colsum(W[640:768])
#define FLAG_OFF 182272               // 256 flags, stride 16 u32 (64B lines)
#define WS_FLOATS (FLAG_OFF + 4096)

__device__ __forceinline__ float sigmoidf_(float x) {
  return 1.0f / (1.0f + expf(-x));
}

__global__ void setup_kernel(const float* __restrict__ W,
                             const float* __restrict__ bias,
                             float* __restrict__ ws) {
  int tid = blockIdx.x * blockDim.x + threadIdx.x;   // 64*256 = 16384 threads
  for (int i = tid; i < 3 * BSZ * NCLS; i += 64 * 256)
    ws[LOG_OFF + i] = 0.0f;
  if (tid < 4096)
    ((unsigned int*)(ws + FLAG_OFF))[tid] = 0u;
  if (tid < G4) {
    float s = 0.0f;
    #pragma unroll 4
    for (int r = 0; r < NCLS; ++r)
      s += W[(size_t)(XDIM + r) * G4 + tid];
    ws[W0_OFF + tid] = bias[tid] + 1e-5f * s;
  }
}

__global__ void __launch_bounds__(NTHR, 1)
lstm_main(const float* __restrict__ xc, const float* __restrict__ xw,
          const float* __restrict__ W,  const float* __restrict__ U,
          const float* __restrict__ bias, const float* __restrict__ Wsm,
          const float* __restrict__ bsv, int* __restrict__ out,
          float* __restrict__ ws)
{
  __shared__ float U_lds[512 * 64];      // 128 KB resident U tile [k][cc]
  __shared__ float ins_lds[2][16 * 132]; // double-buffered staging [b][128]
  __shared__ float zred[2176];           // union: z exchange [32][68] / argmax red
  __shared__ float hl_lds[16 * 17];      // h_new tile [b][16], padded
  __shared__ int   idx_lds[BT];

  float* red_v = zred;                   // [16][33]
  int*   red_i = (int*)(zred + 528);     // [16][33]

  const int tid = threadIdx.x;
  const int blk = blockIdx.x;
  // XCD-local groups: round-robin dispatch -> blk&7 selects XCD
  const int grp = blk & 7;               // batch group == XCD (heuristic)
  const int jt  = blk >> 3;              // 0..31 j-tile
  const int b0  = grp * BT;
  const int j0  = jt * JTS;

  // GEMM mapping: thread = (batch row gb, gate gg, 4-col group j4, K-half kh)
  const int gb  = tid & 15;
  const int gg  = (tid >> 4) & 3;
  const int j4  = (tid >> 6) & 3;
  const int kh  = tid >> 8;                 // 0..1
  const int c0  = gg * 512 + j0 + j4 * 4;   // global column in [0,2048)
  const int cc0 = gg * 16 + j4 * 4;         // LDS column in [0,64)

  // staging mapping: thread = (row srow, 4-float seg sseg)
  const int srow = tid >> 5;                // 0..15
  const int sseg = tid & 31;                // 0..31

  // logits/argmax mapping: thread = (row ub, class-quad um)
  const int ub = tid >> 5;
  const int um = tid & 31;

  // update mapping (tid < 256): thread = (row vb, h-col vj)
  const int vb = (tid >> 4) & 15;
  const int vj = tid & 15;

  float* hbuf   = ws + H_OFF;
  float* logits = ws + LOG_OFF;
  unsigned int* flags = (unsigned int*)(ws + FLAG_OFF);
  unsigned int* myflag   = flags + (grp * 32 + jt) * 16;
  unsigned int* pollflag = flags + (grp * 32 + (tid & 31)) * 16;

  // Load resident U tile: U_lds[k*64 + cc] = U[k][col(cc)]
  {
    int cc  = tid & 63;
    int col = (cc >> 4) * 512 + j0 + (cc & 15);
    int k0  = tid >> 6;  // 0..7
    for (int kk = 0; kk < 64; ++kk) {
      int k = kk * 8 + k0;
      U_lds[k * 64 + cc] = U[(size_t)k * G4 + col];
    }
  }

  // x-feature projection (depth 640, this thread's K-half) for step tt.
  // Double-buffered staging: 1 syncthreads per chunk.
  auto x_part = [&](int tt) -> float4 {
    float4 a4 = make_float4(0.f, 0.f, 0.f, 0.f);
    {
      const float* s0 = xc + ((size_t)(b0 + srow) * TLEN + tt) * NCLS + sseg * 4;
      float4 r = *(const float4*)s0;
      __syncthreads();   // ins_lds free (prior users done)
      *(float4*)(&ins_lds[0][srow * 132 + sseg * 4]) = r;
      __syncthreads();
    }
    #pragma unroll 1
    for (int ch = 0; ch < 5; ++ch) {
      float4 nxt;
      if (ch + 1 < 5) {
        const float* s = xw + ((size_t)(b0 + srow) * TLEN + tt) * WDIM
                       + ch * 128 + sseg * 4;
        nxt = *(const float4*)s;
      }
      const float* wp = W + (size_t)(ch * 128 + kh * 64) * G4 + c0;
      const float* ip = &ins_lds[ch & 1][gb * 132 + kh * 64];
      #pragma unroll 8
      for (int kk = 0; kk < 64; ++kk) {
        float a = ip[kk];
        float4 w4 = *(const float4*)(wp + (size_t)kk * G4);
        a4.x = fmaf(a, w4.x, a4.x);
        a4.y = fmaf(a, w4.y, a4.y);
        a4.z = fmaf(a, w4.z, a4.z);
        a4.w = fmaf(a, w4.w, a4.w);
      }
      if (ch + 1 < 5) {
        *(float4*)(&ins_lds[(ch + 1) & 1][srow * 132 + sseg * 4]) = nxt;
        __syncthreads();
      }
    }
    return a4;
  };

  float creg = 0.0f;      // cell state: thread(<256) owns (b0+vb, j0+vj)
  __syncthreads();
  float4 xacc = x_part(0);

  for (int t = 0; t < TLEN; ++t) {
    float4 acc = xacc;

    if (t == 0) {
      if (kh == 0) {
        const float4 w0 = *(const float4*)(ws + W0_OFF + c0);
        acc.x += w0.x; acc.y += w0.y; acc.z += w0.z; acc.w += w0.w;
      }
    } else {
      // ---- argmax of step t-1 logits (redundant per block) + zero rotation
      {
        const float* lsrc = logits + ((t + 2) % 3) * (BSZ * NCLS)
                          + (b0 + ub) * NCLS + um * 4;
        const float4 bb = *(const float4*)(bsv + um * 4);
        float4 lv = *(const float4*)lsrc;
        float bv = lv.x + bb.x; int bi = um * 4;
        if (lv.y + bb.y > bv) { bv = lv.y + bb.y; bi = um * 4 + 1; }
        if (lv.z + bb.z > bv) { bv = lv.z + bb.z; bi = um * 4 + 2; }
        if (lv.w + bb.w > bv) { bv = lv.w + bb.w; bi = um * 4 + 3; }
        __syncthreads();   // zred free (z-reads of t-1 done behind barrier)
        red_v[ub * 33 + um] = bv; red_i[ub * 33 + um] = bi;
        // zero buf[(t+1)%3] group rows (last read at step t-1, behind barrier)
        float* lz = logits + ((t + 1) % 3) * (BSZ * NCLS) + b0 * NCLS;
        if (tid < 64) lz[jt * 64 + tid] = 0.0f;
        __syncthreads();
        if (um == 0) {
          float v = red_v[ub * 33]; int vi = red_i[ub * 33];
          #pragma unroll
          for (int s = 1; s < 32; ++s) {     // first-max tie-break via idx order
            float v2 = red_v[ub * 33 + s];
            int   i2 = red_i[ub * 33 + s];
            if (v2 > v || (v2 == v && i2 < vi)) { v = v2; vi = i2; }
          }
          idx_lds[ub] = vi;
          if (jt == 0) out[(b0 + ub) * TLEN + (t - 1)] = vi;
        }
        __syncthreads();
      }
      // ---- bias + one-hot word row of W (K-half 0 only)
      if (kh == 0) {
        int wr = XDIM + idx_lds[gb];
        const float4 b4 = *(const float4*)(bias + c0);
        const float4 w4 = *(const float4*)(W + (size_t)wr * G4 + c0);
        acc.x += b4.x + w4.x;  acc.y += b4.y + w4.y;
        acc.z += b4.z + w4.z;  acc.w += b4.w + w4.w;
      }
      // ---- h @ U from LDS-resident tile (double-buffered h staging)
      {
        const float* hprev = hbuf + ((t + 1) & 1) * (BSZ * 512);
        {
          const float* s0 = hprev + (size_t)(b0 + srow) * 512 + sseg * 4;
          float4 r = *(const float4*)s0;
          *(float4*)(&ins_lds[0][srow * 132 + sseg * 4]) = r;
          __syncthreads();
        }
        #pragma unroll 1
        for (int ch = 0; ch < 4; ++ch) {
          float4 nxt;
          if (ch + 1 < 4) {
            const float* s = hprev + (size_t)(b0 + srow) * 512
                           + (ch + 1) * 128 + sseg * 4;
            nxt = *(const float4*)s;
          }
          const float* up = U_lds + (ch * 128 + kh * 64) * 64 + cc0;
          const float* ip = &ins_lds[ch & 1][gb * 132 + kh * 64];
          #pragma unroll 8
          for (int kk = 0; kk < 64; ++kk) {
            float a = ip[kk];
            float4 u4 = *(const float4*)(up + kk * 64);
            acc.x = fmaf(a, u4.x, acc.x);
            acc.y = fmaf(a, u4.y, acc.y);
            acc.z = fmaf(a, u4.z, acc.z);
            acc.w = fmaf(a, u4.w, acc.w);
          }
          if (ch + 1 < 4) {
            *(float4*)(&ins_lds[(ch + 1) & 1][srow * 132 + sseg * 4]) = nxt;
            __syncthreads();
          }
        }
      }
    }

    // ---- z exchange: regroup 4 gates per (b,j), both K-halves
    __syncthreads();                 // zred free (argmax red done / t==0 fresh)
    *(float4*)(zred + (gb * 2 + kh) * 68 + cc0) = acc;
    __syncthreads();

    // ---- gate nonlinearities + cell/hidden update (first 256 threads)
    if (tid < 256) {
      float zi = zred[(vb * 2) * 68 +  0 + vj] + zred[(vb * 2 + 1) * 68 +  0 + vj];
      float zf = zred[(vb * 2) * 68 + 16 + vj] + zred[(vb * 2 + 1) * 68 + 16 + vj];
      float zg = zred[(vb * 2) * 68 + 32 + vj] + zred[(vb * 2 + 1) * 68 + 32 + vj];
      float zo = zred[(vb * 2) * 68 + 48 + vj] + zred[(vb * 2 + 1) * 68 + 48 + vj];
      float iv = sigmoidf_(zi);
      float fv = sigmoidf_(zf);
      float gv = tanhf(zg);
      float ov = sigmoidf_(zo);
      creg = fv * creg + iv * gv;
      float hn = ov * tanhf(creg);
      hbuf[(t & 1) * (BSZ * 512) + (size_t)(b0 + vb) * 512 + j0 + vj] = hn;
      hl_lds[vb * 17 + vj] = hn;
    }
    __syncthreads();

    // ---- logits partial over this block's 16 j, atomic into buf[t%3]
    {
      float p0 = 0.f, p1 = 0.f, p2 = 0.f, p3 = 0.f;
      #pragma unroll
      for (int j = 0; j < 16; ++j) {
        float hv = hl_lds[ub * 17 + j];
        const float4 wv = *(const float4*)(Wsm + (size_t)(j0 + j) * NCLS + um * 4);
        p0 = fmaf(hv, wv.x, p0); p1 = fmaf(hv, wv.y, p1);
        p2 = fmaf(hv, wv.z, p2); p3 = fmaf(hv, wv.w, p3);
      }
      float* ld = logits + (t % 3) * (BSZ * NCLS)
                + (size_t)(b0 + ub) * NCLS + um * 4;
      atomicAdd(ld + 0, p0); atomicAdd(ld + 1, p1);
      atomicAdd(ld + 2, p2); atomicAdd(ld + 3, p3);
    }

    // ---- group barrier: parallel per-block flags, arrive -> overlap -> wait
    __syncthreads();                    // drains each wave's vmcnt (atomics done)
    if (tid == 0) {
      __threadfence();
      __hip_atomic_store(myflag, (unsigned)(t + 1),
                         __ATOMIC_RELEASE, __HIP_MEMORY_SCOPE_AGENT);
    }
    if (t + 1 < TLEN) xacc = x_part(t + 1);   // hides barrier latency
    if (tid < 64) {
      const unsigned tgt = (unsigned)(t + 1);
      for (;;) {
        unsigned v = __hip_atomic_load(pollflag, __ATOMIC_RELAXED,
                                       __HIP_MEMORY_SCOPE_AGENT);
        if (__all(v >= tgt)) break;
        __builtin_amdgcn_s_sleep(1);
      }
      // one acquire to publish remote writes to this CU/XCD
      (void)__hip_atomic_load(pollflag, __ATOMIC_ACQUIRE,
                              __HIP_MEMORY_SCOPE_AGENT);
    }
    __syncthreads();
  }

  // ---- epilogue: argmax for final step (buf (TLEN-1)%3 == 0)
  if (jt == 0) {
    const float* lsrc = logits + ((TLEN - 1) % 3) * (BSZ * NCLS)
                      + (b0 + ub) * NCLS + um * 4;
    const float4 bb = *(const float4*)(bsv + um * 4);
    float4 lv = *(const float4*)lsrc;
    float bv = lv.x + bb.x; int bi = um * 4;
    if (lv.y + bb.y > bv) { bv = lv.y + bb.y; bi = um * 4 + 1; }
    if (lv.z + bb.z > bv) { bv = lv.z + bb.z; bi = um * 4 + 2; }
    if (lv.w + bb.w > bv) { bv = lv.w + bb.w; bi = um * 4 + 3; }
    __syncthreads();
    red_v[ub * 33 + um] = bv; red_i[ub * 33 + um] = bi;
    __syncthreads();
    if (um == 0) {
      float v = red_v[ub * 33]; int vi = red_i[ub * 33];
      #pragma unroll
      for (int s = 1; s < 32; ++s) {
        float v2 = red_v[ub * 33 + s];
        int   i2 = red_i[ub * 33 + s];
        if (v2 > v || (v2 == v && i2 < vi)) { v = v2; vi = i2; }
      }
      out[(b0 + ub) * TLEN + (TLEN - 1)] = vi;
    }
  }
}

extern "C" void kernel_launch(void* const* d_in, const int* in_sizes, int n_in,
                              void* d_out, int out_size, void* d_ws, size_t ws_size,
                              hipStream_t stream) {
  (void)in_sizes; (void)n_in; (void)out_size; (void)ws_size;
  const float* xc  = (const float*)d_in[0];
  const float* xw  = (const float*)d_in[1];
  const float* W   = (const float*)d_in[2];
  const float* U   = (const float*)d_in[3];
  const float* b   = (const float*)d_in[4];
  const float* Wsm = (const float*)d_in[5];
  const float* bs  = (const float*)d_in[6];
  int*   out = (int*)d_out;
  float* ws  = (float*)d_ws;

  hipLaunchKernelGGL(setup_kernel, dim3(64), dim3(256), 0, stream, W, b, ws);

  void* args[] = { (void*)&xc, (void*)&xw, (void*)&W, (void*)&U, (void*)&b,
                   (void*)&Wsm, (void*)&bs, (void*)&out, (void*)&ws };
  hipLaunchCooperativeKernel((const void*)lstm_main, dim3(NBLK), dim3(NTHR),
                             args, 0, stream);
}

// Round 4
// 10094.587 us; speedup vs baseline: 1.1369x; 1.0816x over previous
//
#include <hip/hip_runtime.h>
#include <math.h>

// Problem dims
#define BSZ   128
#define TLEN  256
#define NCLS  128
#define WDIM  512
#define XDIM  640       // NC + WD
#define G4    2048      // 4*UNITS

// Geometry: 8 batch-groups (XCD-local) x 32 j-tiles = 256 blocks, 512 threads
#define BT    16        // batch rows per group
#define JTS   16        // h columns per block
#define NBLK  256
#define NTHR  512
#define KCH   8         // chunk length (steps of x-projection kept in regs)

// ws layout (float offsets) — total ~750 KB (proven to fit in R1/R2)
#define H_OFF    0                    // 2 * 128 * 512 h double buffer
#define LOG_OFF  131072               // 3 * 128 * 128 logits triple buffer
#define W0_OFF   180224               // 2048: bias + 1e-5*colsum(W[640:768])
#define FLAG_OFF 182272               // 256 flags, stride 16 u32 (64B lines)

__device__ __forceinline__ float sigmoidf_(float x) {
  return 1.0f / (1.0f + expf(-x));
}

__global__ void setup_kernel(const float* __restrict__ W,
                             const float* __restrict__ bias,
                             float* __restrict__ ws) {
  int tid = blockIdx.x * blockDim.x + threadIdx.x;   // 64*256 = 16384 threads
  for (int i = tid; i < 3 * BSZ * NCLS; i += 64 * 256)
    ws[LOG_OFF + i] = 0.0f;
  if (tid < 4096)
    ((unsigned int*)(ws + FLAG_OFF))[tid] = 0u;
  if (tid < G4) {
    float s = 0.0f;
    #pragma unroll 4
    for (int r = 0; r < NCLS; ++r)
      s += W[(size_t)(XDIM + r) * G4 + tid];
    ws[W0_OFF + tid] = bias[tid] + 1e-5f * s;
  }
}

__global__ void __launch_bounds__(NTHR, 1)
lstm_main(const float* __restrict__ xc, const float* __restrict__ xw,
          const float* __restrict__ W,  const float* __restrict__ U,
          const float* __restrict__ bias, const float* __restrict__ Wsm,
          const float* __restrict__ bsv, int* __restrict__ out,
          float* __restrict__ ws)
{
  __shared__ float U_lds[512 * 64];      // 128 KB resident U tile [k][cc]
  __shared__ float ins_lds[2][2176];     // staging/zred; chunk GEMM W-tile alias
  __shared__ float wsm_lds[16 * 128];    // resident Wsm tile [j][m]
  __shared__ float hl_lds[16 * 17];      // h_new tile [b][16], padded
  __shared__ int   idx_lds[BT];

  float* zred  = &ins_lds[0][0];         // z exchange [32][68] (2176 floats)
  float* Wt    = &ins_lds[0][0];         // chunk GEMM W-tile [64][64] (4096 fl)
  float* red_v = zred;                   // argmax scratch [16][33]
  int*   red_i = (int*)(zred + 528);     // [16][33]

  const int tid = threadIdx.x;
  const int blk = blockIdx.x;
  // XCD-local groups: round-robin dispatch -> blk&7 selects XCD
  const int grp = blk & 7;               // batch group == XCD (heuristic)
  const int jt  = blk >> 3;              // 0..31 j-tile
  const int b0  = grp * BT;
  const int j0  = jt * JTS;

  // GEMM mapping: thread = (batch row gb, gate gg, 4-col group j4, K-half kh)
  const int gb  = tid & 15;
  const int gg  = (tid >> 4) & 3;
  const int j4  = (tid >> 6) & 3;
  const int kh  = tid >> 8;                 // 0..1
  const int c0  = gg * 512 + j0 + j4 * 4;   // global column in [0,2048)
  const int cc0 = gg * 16 + j4 * 4;         // LDS column in [0,64)

  // staging mapping: thread = (row srow, 4-float seg sseg)
  const int srow = tid >> 5;                // 0..15
  const int sseg = tid & 31;                // 0..31

  // logits/argmax mapping: thread = (row ub, class-quad um)
  const int ub = tid >> 5;
  const int um = tid & 31;

  // update mapping (tid < 256): thread = (row vb, h-col vj)
  const int vb = (tid >> 4) & 15;
  const int vj = tid & 15;

  float* hbuf   = ws + H_OFF;
  float* logits = ws + LOG_OFF;
  unsigned int* flags = (unsigned int*)(ws + FLAG_OFF);
  unsigned int* myflag   = flags + (grp * 32 + jt) * 16;
  unsigned int* pollflag = flags + (grp * 32 + (tid & 31)) * 16;

  // Load resident U tile: U_lds[k*64 + cc] = U[k][col(cc)]
  {
    int cc  = tid & 63;
    int col = (cc >> 4) * 512 + j0 + (cc & 15);
    int k0  = tid >> 6;  // 0..7
    for (int kk = 0; kk < 64; ++kk) {
      int k = kk * 8 + k0;
      U_lds[k * 64 + cc] = U[(size_t)k * G4 + col];
    }
  }
  // Load resident Wsm tile: wsm_lds[j][m]
  {
    int row = tid >> 5, col4 = tid & 31;
    *(float4*)(&wsm_lds[row * 128 + col4 * 4]) =
        *(const float4*)(Wsm + (size_t)(j0 + row) * NCLS + col4 * 4);
  }

  // ---- chunk GEMM: xq[s] (kh-partial x-projection for this thread's
  // (row gb, cols c0..c0+3)) for steps tt0..tt0+7. W-tile staged in LDS
  // (read once per chunk); x rows read direct from global (L1/L2 shared).
  float4 xq[KCH];
  auto chunk_gemm = [&](int tt0) {
    #pragma unroll
    for (int s = 0; s < KCH; ++s) xq[s] = make_float4(0.f, 0.f, 0.f, 0.f);
    #pragma unroll 1
    for (int kt = 0; kt < 10; ++kt) {          // ten 64-deep k-tiles
      // stage W-tile [64 k][64 cols] -> Wt (2 float4 per thread)
      int id0 = tid,       k0t = id0 >> 4, cg0 = id0 & 15;
      int id1 = tid + 512, k1t = id1 >> 4, cg1 = id1 & 15;
      int col0 = (cg0 >> 2) * 512 + j0 + (cg0 & 3) * 4;
      int col1 = (cg1 >> 2) * 512 + j0 + (cg1 & 3) * 4;
      float4 wv0 = *(const float4*)(W + (size_t)(kt * 64 + k0t) * G4 + col0);
      float4 wv1 = *(const float4*)(W + (size_t)(kt * 64 + k1t) * G4 + col1);
      __syncthreads();                         // prior Wt readers done
      *(float4*)(Wt + k0t * 64 + cg0 * 4) = wv0;
      *(float4*)(Wt + k1t * 64 + cg1 * 4) = wv1;
      __syncthreads();                         // tile visible
      const float* wp = Wt + (kh * 32) * 64 + cc0;
      #pragma unroll
      for (int s = 0; s < KCH; ++s) {
        int tt = tt0 + s;
        const float* src = (kt < 2)
          ? xc + ((size_t)(b0 + gb) * TLEN + tt) * NCLS + kt * 64 + kh * 32
          : xw + ((size_t)(b0 + gb) * TLEN + tt) * WDIM + (kt * 64 - 128) + kh * 32;
        float xr[32];
        #pragma unroll
        for (int i = 0; i < 8; ++i)
          *(float4*)(&xr[4 * i]) = *(const float4*)(src + 4 * i);
        #pragma unroll
        for (int kk = 0; kk < 32; ++kk) {
          float a = xr[kk];
          float4 w4 = *(const float4*)(wp + kk * 64);
          xq[s].x = fmaf(a, w4.x, xq[s].x);
          xq[s].y = fmaf(a, w4.y, xq[s].y);
          xq[s].z = fmaf(a, w4.z, xq[s].z);
          xq[s].w = fmaf(a, w4.w, xq[s].w);
        }
      }
    }
  };

  float creg = 0.0f;      // cell state: thread(<256) owns (b0+vb, j0+vj)

  __syncthreads();        // U_lds / wsm_lds ready
  chunk_gemm(0);          // steps 0..7
  __syncthreads();        // Wt readers done before zred reuse

  for (int t = 0; t < TLEN; ++t) {
    float4 acc = xq[0];
    #pragma unroll
    for (int s = 0; s < KCH - 1; ++s) xq[s] = xq[s + 1];   // shift register

    if (t == 0) {
      if (kh == 0) {
        const float4 w0 = *(const float4*)(ws + W0_OFF + c0);
        acc.x += w0.x; acc.y += w0.y; acc.z += w0.z; acc.w += w0.w;
      }
    } else {
      // ---- argmax of step t-1 logits (redundant per block) + zero rotation
      {
        const float* lsrc = logits + ((t + 2) % 3) * (BSZ * NCLS)
                          + (b0 + ub) * NCLS + um * 4;
        const float4 bb = *(const float4*)(bsv + um * 4);
        float4 lv = *(const float4*)lsrc;
        float bv = lv.x + bb.x; int bi = um * 4;
        if (lv.y + bb.y > bv) { bv = lv.y + bb.y; bi = um * 4 + 1; }
        if (lv.z + bb.z > bv) { bv = lv.z + bb.z; bi = um * 4 + 2; }
        if (lv.w + bb.w > bv) { bv = lv.w + bb.w; bi = um * 4 + 3; }
        red_v[ub * 33 + um] = bv; red_i[ub * 33 + um] = bi;
        // zero buf[(t+1)%3] group rows (last read at step t-1, behind barrier)
        float* lz = logits + ((t + 1) % 3) * (BSZ * NCLS) + b0 * NCLS;
        if (tid < 64) lz[jt * 64 + tid] = 0.0f;
        __syncthreads();
        if (um == 0) {
          float v = red_v[ub * 33]; int vi = red_i[ub * 33];
          #pragma unroll
          for (int s = 1; s < 32; ++s) {     // first-max tie-break via idx order
            float v2 = red_v[ub * 33 + s];
            int   i2 = red_i[ub * 33 + s];
            if (v2 > v || (v2 == v && i2 < vi)) { v = v2; vi = i2; }
          }
          idx_lds[ub] = vi;
          if (jt == 0) out[(b0 + ub) * TLEN + (t - 1)] = vi;
        }
        __syncthreads();
      }
      // ---- bias + one-hot word row of W (K-half 0 only)
      if (kh == 0) {
        int wr = XDIM + idx_lds[gb];
        const float4 b4 = *(const float4*)(bias + c0);
        const float4 w4 = *(const float4*)(W + (size_t)wr * G4 + c0);
        acc.x += b4.x + w4.x;  acc.y += b4.y + w4.y;
        acc.z += b4.z + w4.z;  acc.w += b4.w + w4.w;
      }
      // ---- h @ U from LDS-resident tile (double-buffered h staging)
      {
        const float* hprev = hbuf + ((t + 1) & 1) * (BSZ * 512);
        {
          const float* s0 = hprev + (size_t)(b0 + srow) * 512 + sseg * 4;
          float4 r = *(const float4*)s0;
          *(float4*)(&ins_lds[0][srow * 132 + sseg * 4]) = r;
          __syncthreads();
        }
        #pragma unroll 1
        for (int ch = 0; ch < 4; ++ch) {
          float4 nxt;
          if (ch + 1 < 4) {
            const float* s = hprev + (size_t)(b0 + srow) * 512
                           + (ch + 1) * 128 + sseg * 4;
            nxt = *(const float4*)s;
          }
          const float* up = U_lds + (ch * 128 + kh * 64) * 64 + cc0;
          const float* ip = &ins_lds[ch & 1][gb * 132 + kh * 64];
          #pragma unroll 8
          for (int kk = 0; kk < 64; ++kk) {
            float a = ip[kk];
            float4 u4 = *(const float4*)(up + kk * 64);
            acc.x = fmaf(a, u4.x, acc.x);
            acc.y = fmaf(a, u4.y, acc.y);
            acc.z = fmaf(a, u4.z, acc.z);
            acc.w = fmaf(a, u4.w, acc.w);
          }
          if (ch + 1 < 4) {
            *(float4*)(&ins_lds[(ch + 1) & 1][srow * 132 + sseg * 4]) = nxt;
            __syncthreads();
          }
        }
      }
    }

    // ---- z exchange into zred (= ins_lds[0]; its last readers synced at ch2)
    *(float4*)(zred + (gb * 2 + kh) * 68 + cc0) = acc;
    __syncthreads();

    // ---- gate nonlinearities + cell/hidden update (first 256 threads)
    if (tid < 256) {
      float zi = zred[(vb * 2) * 68 +  0 + vj] + zred[(vb * 2 + 1) * 68 +  0 + vj];
      float zf = zred[(vb * 2) * 68 + 16 + vj] + zred[(vb * 2 + 1) * 68 + 16 + vj];
      float zg = zred[(vb * 2) * 68 + 32 + vj] + zred[(vb * 2 + 1) * 68 + 32 + vj];
      float zo = zred[(vb * 2) * 68 + 48 + vj] + zred[(vb * 2 + 1) * 68 + 48 + vj];
      float iv = sigmoidf_(zi);
      float fv = sigmoidf_(zf);
      float gv = tanhf(zg);
      float ov = sigmoidf_(zo);
      creg = fv * creg + iv * gv;
      float hn = ov * tanhf(creg);
      hbuf[(t & 1) * (BSZ * 512) + (size_t)(b0 + vb) * 512 + j0 + vj] = hn;
      hl_lds[vb * 17 + vj] = hn;
    }
    __syncthreads();

    // ---- logits partial over this block's 16 j, atomic into buf[t%3]
    {
      float p0 = 0.f, p1 = 0.f, p2 = 0.f, p3 = 0.f;
      #pragma unroll
      for (int j = 0; j < 16; ++j) {
        float hv = hl_lds[ub * 17 + j];
        const float4 wv = *(const float4*)(&wsm_lds[j * 128 + um * 4]);
        p0 = fmaf(hv, wv.x, p0); p1 = fmaf(hv, wv.y, p1);
        p2 = fmaf(hv, wv.z, p2); p3 = fmaf(hv, wv.w, p3);
      }
      float* ld = logits + (t % 3) * (BSZ * NCLS)
                + (size_t)(b0 + ub) * NCLS + um * 4;
      atomicAdd(ld + 0, p0); atomicAdd(ld + 1, p1);
      atomicAdd(ld + 2, p2); atomicAdd(ld + 3, p3);
    }

    // ---- group barrier: arrive -> (chunk GEMM overlap) -> wait
    __syncthreads();                    // all waves' logits atomics issued
    if (tid == 0) {
      __threadfence();
      __hip_atomic_store(myflag, (unsigned)(t + 1),
                         __ATOMIC_RELEASE, __HIP_MEMORY_SCOPE_AGENT);
    }
    if (((t + 1) & (KCH - 1)) == 0 && t + 1 < TLEN)
      chunk_gemm(t + 1);                // heavy, recurrence-independent work
    if (tid < 64) {
      const unsigned tgt = (unsigned)(t + 1);
      for (;;) {
        unsigned v = __hip_atomic_load(pollflag, __ATOMIC_RELAXED,
                                       __HIP_MEMORY_SCOPE_AGENT);
        if (__all(v >= tgt)) break;
        __builtin_amdgcn_s_sleep(1);
      }
      // one acquire to publish remote writes to this CU/XCD
      (void)__hip_atomic_load(pollflag, __ATOMIC_ACQUIRE,
                              __HIP_MEMORY_SCOPE_AGENT);
    }
    __syncthreads();   // also separates chunk-GEMM Wt reads from next-step LDS writes
  }

  // ---- epilogue: argmax for final step (buf (TLEN-1)%3 == 0)
  if (jt == 0) {
    const float* lsrc = logits + ((TLEN - 1) % 3) * (BSZ * NCLS)
                      + (b0 + ub) * NCLS + um * 4;
    const float4 bb = *(const float4*)(bsv + um * 4);
    float4 lv = *(const float4*)lsrc;
    float bv = lv.x + bb.x; int bi = um * 4;
    if (lv.y + bb.y > bv) { bv = lv.y + bb.y; bi = um * 4 + 1; }
    if (lv.z + bb.z > bv) { bv = lv.z + bb.z; bi = um * 4 + 2; }
    if (lv.w + bb.w > bv) { bv = lv.w + bb.w; bi = um * 4 + 3; }
    __syncthreads();
    red_v[ub * 33 + um] = bv; red_i[ub * 33 + um] = bi;
    __syncthreads();
    if (um == 0) {
      float v = red_v[ub * 33]; int vi = red_i[ub * 33];
      #pragma unroll
      for (int s = 1; s < 32; ++s) {
        float v2 = red_v[ub * 33 + s];
        int   i2 = red_i[ub * 33 + s];
        if (v2 > v || (v2 == v && i2 < vi)) { v = v2; vi = i2; }
      }
      out[(b0 + ub) * TLEN + (TLEN - 1)] = vi;
    }
  }
}

extern "C" void kernel_launch(void* const* d_in, const int* in_sizes, int n_in,
                              void* d_out, int out_size, void* d_ws, size_t ws_size,
                              hipStream_t stream) {
  (void)in_sizes; (void)n_in; (void)out_size; (void)ws_size;
  const float* xc  = (const float*)d_in[0];
  const float* xw  = (const float*)d_in[1];
  const float* W   = (const float*)d_in[2];
  const float* U   = (const float*)d_in[3];
  const float* b   = (const float*)d_in[4];
  const float* Wsm = (const float*)d_in[5];
  const float* bs  = (const float*)d_in[6];
  int*   out = (int*)d_out;
  float* ws  = (float*)d_ws;

  hipLaunchKernelGGL(setup_kernel, dim3(64), dim3(256), 0, stream, W, b, ws);

  void* args[] = { (void*)&xc, (void*)&xw, (void*)&W, (void*)&U, (void*)&b,
                   (void*)&Wsm, (void*)&bs, (void*)&out, (void*)&ws };
  hipLaunchCooperativeKernel((const void*)lstm_main, dim3(NBLK), dim3(NTHR),
                             args, 0, stream);
}

// Round 5
// 8739.109 us; speedup vs baseline: 1.3132x; 1.1551x over previous
//
#include <hip/hip_runtime.h>
#include <math.h>

// Problem dims
#define BSZ   128
#define TLEN  256
#define NCLS  128
#define WDIM  512
#define XDIM  640       // NC + WD
#define G4    2048      // 4*UNITS

// Geometry: 8 batch-groups (XCD-local) x 32 j-tiles = 256 blocks, 512 threads
#define BT    16        // batch rows per group
#define JTS   16        // h columns per block
#define NBLK  256
#define NTHR  512
#define KCH   8         // chunk length (steps of x-projection kept in regs)

// ws layout (float offsets) — total ~750 KB (proven to fit in R1/R2)
#define H_OFF    0                    // 2 * 128 * 512 h double buffer
#define LOG_OFF  131072               // 3 * 128 * 128 logits triple buffer
#define W0_OFF   180224               // 2048: bias + 1e-5*colsum(W[640:768])
#define FLAG_OFF 182272               // 256 flags, stride 16 u32 (64B lines)

typedef unsigned long long ull;

__device__ __forceinline__ float sigmoidf_(float x) {
  return 1.0f / (1.0f + expf(-x));
}

// relaxed device-scope 16B load as 2x b64 atomics (IC-coherent, NO buffer_inv)
__device__ __forceinline__ float4 ld_dev16(const float* p) {
  const ull* q = (const ull*)p;
  ull a = __hip_atomic_load(q,     __ATOMIC_RELAXED, __HIP_MEMORY_SCOPE_AGENT);
  ull b = __hip_atomic_load(q + 1, __ATOMIC_RELAXED, __HIP_MEMORY_SCOPE_AGENT);
  float4 r;
  ((ull*)&r)[0] = a;
  ((ull*)&r)[1] = b;
  return r;
}

__global__ void setup_kernel(const float* __restrict__ W,
                             const float* __restrict__ bias,
                             float* __restrict__ ws) {
  int tid = blockIdx.x * blockDim.x + threadIdx.x;   // 64*256 = 16384 threads
  for (int i = tid; i < 3 * BSZ * NCLS; i += 64 * 256)
    ws[LOG_OFF + i] = 0.0f;
  if (tid < 4096)
    ((unsigned int*)(ws + FLAG_OFF))[tid] = 0u;
  if (tid < G4) {
    float s = 0.0f;
    #pragma unroll 4
    for (int r = 0; r < NCLS; ++r)
      s += W[(size_t)(XDIM + r) * G4 + tid];
    ws[W0_OFF + tid] = bias[tid] + 1e-5f * s;
  }
}

__global__ void __launch_bounds__(NTHR, 1)
lstm_main(const float* __restrict__ xc, const float* __restrict__ xw,
          const float* __restrict__ W,  const float* __restrict__ U,
          const float* __restrict__ bias, const float* __restrict__ Wsm,
          const float* __restrict__ bsv, int* __restrict__ out,
          float* __restrict__ ws)
{
  __shared__ float U_lds[512 * 64];      // 128 KB resident U tile [k][cc]
  __shared__ float ins_lds[2][2176];     // staging/zred; chunk GEMM W-tile alias
  __shared__ float wsm_lds[16 * 128];    // resident Wsm tile [j][m]
  __shared__ float hl_lds[16 * 17];      // h_new tile [b][16], padded
  __shared__ int   idx_lds[BT];

  float* zred  = &ins_lds[0][0];         // z exchange [32][68] (2176 floats)
  float* Wt    = &ins_lds[0][0];         // chunk GEMM W-tile [64][64] (4096 fl)
  float* red_v = zred;                   // argmax scratch [16][33]
  int*   red_i = (int*)(zred + 528);     // [16][33]

  const int tid = threadIdx.x;
  const int blk = blockIdx.x;
  // XCD-local groups: round-robin dispatch -> blk&7 selects XCD (perf heuristic
  // only; correctness now relies solely on memory-side relaxed atomics)
  const int grp = blk & 7;               // batch group
  const int jt  = blk >> 3;              // 0..31 j-tile
  const int b0  = grp * BT;
  const int j0  = jt * JTS;

  // GEMM mapping: thread = (batch row gb, gate gg, 4-col group j4, K-half kh)
  const int gb  = tid & 15;
  const int gg  = (tid >> 4) & 3;
  const int j4  = (tid >> 6) & 3;
  const int kh  = tid >> 8;                 // 0..1
  const int c0  = gg * 512 + j0 + j4 * 4;   // global column in [0,2048)
  const int cc0 = gg * 16 + j4 * 4;         // LDS column in [0,64)

  // staging mapping: thread = (row srow, 4-float seg sseg)
  const int srow = tid >> 5;                // 0..15
  const int sseg = tid & 31;                // 0..31

  // logits/argmax mapping: thread = (row ub, class-quad um)
  const int ub = tid >> 5;
  const int um = tid & 31;

  // update mapping (tid < 256): thread = (row vb, h-col vj)
  const int vb = (tid >> 4) & 15;
  const int vj = tid & 15;

  float* hbuf   = ws + H_OFF;
  float* logits = ws + LOG_OFF;
  unsigned int* flags = (unsigned int*)(ws + FLAG_OFF);
  unsigned int* myflag   = flags + (grp * 32 + jt) * 16;
  unsigned int* pollflag = flags + (grp * 32 + (tid & 31)) * 16;

  // Load resident U tile: U_lds[k*64 + cc] = U[k][col(cc)]
  {
    int cc  = tid & 63;
    int col = (cc >> 4) * 512 + j0 + (cc & 15);
    int k0  = tid >> 6;  // 0..7
    for (int kk = 0; kk < 64; ++kk) {
      int k = kk * 8 + k0;
      U_lds[k * 64 + cc] = U[(size_t)k * G4 + col];
    }
  }
  // Load resident Wsm tile: wsm_lds[j][m]
  {
    int row = tid >> 5, col4 = tid & 31;
    *(float4*)(&wsm_lds[row * 128 + col4 * 4]) =
        *(const float4*)(Wsm + (size_t)(j0 + row) * NCLS + col4 * 4);
  }

  // ---- chunk GEMM: xq[s] (kh-partial x-projection for this thread's
  // (row gb, cols c0..c0+3)) for steps tt0..tt0+7. W-tile staged in LDS
  // (read once per chunk); x rows read direct from global (L1/L2 shared,
  // read-only -> plain cached loads are safe and now stay L2-resident).
  float4 xq[KCH];
  auto chunk_gemm = [&](int tt0) {
    #pragma unroll
    for (int s = 0; s < KCH; ++s) xq[s] = make_float4(0.f, 0.f, 0.f, 0.f);
    #pragma unroll 1
    for (int kt = 0; kt < 10; ++kt) {          // ten 64-deep k-tiles
      // stage W-tile [64 k][64 cols] -> Wt (2 float4 per thread)
      int id0 = tid,       k0t = id0 >> 4, cg0 = id0 & 15;
      int id1 = tid + 512, k1t = id1 >> 4, cg1 = id1 & 15;
      int col0 = (cg0 >> 2) * 512 + j0 + (cg0 & 3) * 4;
      int col1 = (cg1 >> 2) * 512 + j0 + (cg1 & 3) * 4;
      float4 wv0 = *(const float4*)(W + (size_t)(kt * 64 + k0t) * G4 + col0);
      float4 wv1 = *(const float4*)(W + (size_t)(kt * 64 + k1t) * G4 + col1);
      __syncthreads();                         // prior Wt readers done
      *(float4*)(Wt + k0t * 64 + cg0 * 4) = wv0;
      *(float4*)(Wt + k1t * 64 + cg1 * 4) = wv1;
      __syncthreads();                         // tile visible
      const float* wp = Wt + (kh * 32) * 64 + cc0;
      #pragma unroll
      for (int s = 0; s < KCH; ++s) {
        int tt = tt0 + s;
        const float* src = (kt < 2)
          ? xc + ((size_t)(b0 + gb) * TLEN + tt) * NCLS + kt * 64 + kh * 32
          : xw + ((size_t)(b0 + gb) * TLEN + tt) * WDIM + (kt * 64 - 128) + kh * 32;
        float xr[32];
        #pragma unroll
        for (int i = 0; i < 8; ++i)
          *(float4*)(&xr[4 * i]) = *(const float4*)(src + 4 * i);
        #pragma unroll
        for (int kk = 0; kk < 32; ++kk) {
          float a = xr[kk];
          float4 w4 = *(const float4*)(wp + kk * 64);
          xq[s].x = fmaf(a, w4.x, xq[s].x);
          xq[s].y = fmaf(a, w4.y, xq[s].y);
          xq[s].z = fmaf(a, w4.z, xq[s].z);
          xq[s].w = fmaf(a, w4.w, xq[s].w);
        }
      }
    }
  };

  float creg = 0.0f;      // cell state: thread(<256) owns (b0+vb, j0+vj)

  __syncthreads();        // U_lds / wsm_lds ready
  chunk_gemm(0);          // steps 0..7
  __syncthreads();        // Wt readers done before zred reuse

  for (int t = 0; t < TLEN; ++t) {
    float4 acc = xq[0];
    #pragma unroll
    for (int s = 0; s < KCH - 1; ++s) xq[s] = xq[s + 1];   // shift register

    if (t == 0) {
      if (kh == 0) {
        const float4 w0 = *(const float4*)(ws + W0_OFF + c0);
        acc.x += w0.x; acc.y += w0.y; acc.z += w0.z; acc.w += w0.w;
      }
    } else {
      // ---- argmax of step t-1 logits (redundant per block) + zero rotation
      {
        const float* lsrc = logits + ((t + 2) % 3) * (BSZ * NCLS)
                          + (b0 + ub) * NCLS + um * 4;
        const float4 bb = *(const float4*)(bsv + um * 4);
        float4 lv = ld_dev16(lsrc);            // IC-coherent, no cache inv
        float bv = lv.x + bb.x; int bi = um * 4;
        if (lv.y + bb.y > bv) { bv = lv.y + bb.y; bi = um * 4 + 1; }
        if (lv.z + bb.z > bv) { bv = lv.z + bb.z; bi = um * 4 + 2; }
        if (lv.w + bb.w > bv) { bv = lv.w + bb.w; bi = um * 4 + 3; }
        red_v[ub * 33 + um] = bv; red_i[ub * 33 + um] = bi;
        // zero buf[(t+1)%3] group rows (last read at step t-1, behind barrier)
        // atomic store: must be IC-visible before other blocks' step-t+1 adds
        float* lz = logits + ((t + 1) % 3) * (BSZ * NCLS) + b0 * NCLS;
        if (tid < 64)
          __hip_atomic_store(&lz[jt * 64 + tid], 0.0f,
                             __ATOMIC_RELAXED, __HIP_MEMORY_SCOPE_AGENT);
        __syncthreads();
        if (um == 0) {
          float v = red_v[ub * 33]; int vi = red_i[ub * 33];
          #pragma unroll
          for (int s = 1; s < 32; ++s) {     // first-max tie-break via idx order
            float v2 = red_v[ub * 33 + s];
            int   i2 = red_i[ub * 33 + s];
            if (v2 > v || (v2 == v && i2 < vi)) { v = v2; vi = i2; }
          }
          idx_lds[ub] = vi;
          if (jt == 0) out[(b0 + ub) * TLEN + (t - 1)] = vi;
        }
        __syncthreads();
      }
      // ---- bias + one-hot word row of W (K-half 0 only)
      if (kh == 0) {
        int wr = XDIM + idx_lds[gb];
        const float4 b4 = *(const float4*)(bias + c0);
        const float4 w4 = *(const float4*)(W + (size_t)wr * G4 + c0);
        acc.x += b4.x + w4.x;  acc.y += b4.y + w4.y;
        acc.z += b4.z + w4.z;  acc.w += b4.w + w4.w;
      }
      // ---- h @ U from LDS-resident tile (double-buffered h staging;
      //      h loads are relaxed device-scope atomics -> IC-fresh, no inv)
      {
        const float* hprev = hbuf + ((t + 1) & 1) * (BSZ * 512);
        {
          float4 r = ld_dev16(hprev + (size_t)(b0 + srow) * 512 + sseg * 4);
          *(float4*)(&ins_lds[0][srow * 132 + sseg * 4]) = r;
          __syncthreads();
        }
        #pragma unroll 1
        for (int ch = 0; ch < 4; ++ch) {
          float4 nxt;
          if (ch + 1 < 4) {
            nxt = ld_dev16(hprev + (size_t)(b0 + srow) * 512
                           + (ch + 1) * 128 + sseg * 4);
          }
          const float* up = U_lds + (ch * 128 + kh * 64) * 64 + cc0;
          const float* ip = &ins_lds[ch & 1][gb * 132 + kh * 64];
          #pragma unroll 8
          for (int kk = 0; kk < 64; ++kk) {
            float a = ip[kk];
            float4 u4 = *(const float4*)(up + kk * 64);
            acc.x = fmaf(a, u4.x, acc.x);
            acc.y = fmaf(a, u4.y, acc.y);
            acc.z = fmaf(a, u4.z, acc.z);
            acc.w = fmaf(a, u4.w, acc.w);
          }
          if (ch + 1 < 4) {
            *(float4*)(&ins_lds[(ch + 1) & 1][srow * 132 + sseg * 4]) = nxt;
            __syncthreads();
          }
        }
      }
    }

    // ---- z exchange into zred (= ins_lds[0]; its last readers synced at ch2)
    *(float4*)(zred + (gb * 2 + kh) * 68 + cc0) = acc;
    __syncthreads();

    // ---- gate nonlinearities + cell/hidden update (first 256 threads)
    if (tid < 256) {
      float zi = zred[(vb * 2) * 68 +  0 + vj] + zred[(vb * 2 + 1) * 68 +  0 + vj];
      float zf = zred[(vb * 2) * 68 + 16 + vj] + zred[(vb * 2 + 1) * 68 + 16 + vj];
      float zg = zred[(vb * 2) * 68 + 32 + vj] + zred[(vb * 2 + 1) * 68 + 32 + vj];
      float zo = zred[(vb * 2) * 68 + 48 + vj] + zred[(vb * 2 + 1) * 68 + 48 + vj];
      float iv = sigmoidf_(zi);
      float fv = sigmoidf_(zf);
      float gv = tanhf(zg);
      float ov = sigmoidf_(zo);
      creg = fv * creg + iv * gv;
      float hn = ov * tanhf(creg);
      // relaxed device-scope store -> lands at IC, visible after vmcnt drain
      __hip_atomic_store(hbuf + (t & 1) * (BSZ * 512)
                         + (size_t)(b0 + vb) * 512 + j0 + vj, hn,
                         __ATOMIC_RELAXED, __HIP_MEMORY_SCOPE_AGENT);
      hl_lds[vb * 17 + vj] = hn;
    }
    __syncthreads();

    // ---- logits partial over this block's 16 j, atomic into buf[t%3]
    {
      float p0 = 0.f, p1 = 0.f, p2 = 0.f, p3 = 0.f;
      #pragma unroll
      for (int j = 0; j < 16; ++j) {
        float hv = hl_lds[ub * 17 + j];
        const float4 wv = *(const float4*)(&wsm_lds[j * 128 + um * 4]);
        p0 = fmaf(hv, wv.x, p0); p1 = fmaf(hv, wv.y, p1);
        p2 = fmaf(hv, wv.z, p2); p3 = fmaf(hv, wv.w, p3);
      }
      float* ld = logits + (t % 3) * (BSZ * NCLS)
                + (size_t)(b0 + ub) * NCLS + um * 4;
      atomicAdd(ld + 0, p0); atomicAdd(ld + 1, p1);
      atomicAdd(ld + 2, p2); atomicAdd(ld + 3, p3);
    }

    // ---- group barrier: relaxed flags only — NO threadfence / acquire
    // (those lower to buffer_wbl2 / buffer_inv = full-L2 writeback+invalidate
    //  per block per step — the R1-R4 ~35us/step floor).
    // Ordering: __syncthreads drains vmcnt(0) per wave, so all h stores /
    // logit atomics are ack'd at the coherence point before tid0's flag store.
    __syncthreads();
    if (tid == 0)
      __hip_atomic_store(myflag, (unsigned)(t + 1),
                         __ATOMIC_RELAXED, __HIP_MEMORY_SCOPE_AGENT);
    if (((t + 1) & (KCH - 1)) == 0 && t + 1 < TLEN)
      chunk_gemm(t + 1);                // heavy, recurrence-independent work
    if (tid < 64) {
      const unsigned tgt = (unsigned)(t + 1);
      for (;;) {
        unsigned v = __hip_atomic_load(pollflag, __ATOMIC_RELAXED,
                                       __HIP_MEMORY_SCOPE_AGENT);
        if (__all(v >= tgt)) break;
        __builtin_amdgcn_s_sleep(1);
      }
    }
    __syncthreads();   // also separates chunk-GEMM Wt reads from next-step LDS writes
  }

  // ---- epilogue: argmax for final step (buf (TLEN-1)%3 == 0)
  if (jt == 0) {
    const float* lsrc = logits + ((TLEN - 1) % 3) * (BSZ * NCLS)
                      + (b0 + ub) * NCLS + um * 4;
    const float4 bb = *(const float4*)(bsv + um * 4);
    float4 lv = ld_dev16(lsrc);
    float bv = lv.x + bb.x; int bi = um * 4;
    if (lv.y + bb.y > bv) { bv = lv.y + bb.y; bi = um * 4 + 1; }
    if (lv.z + bb.z > bv) { bv = lv.z + bb.z; bi = um * 4 + 2; }
    if (lv.w + bb.w > bv) { bv = lv.w + bb.w; bi = um * 4 + 3; }
    __syncthreads();
    red_v[ub * 33 + um] = bv; red_i[ub * 33 + um] = bi;
    __syncthreads();
    if (um == 0) {
      float v = red_v[ub * 33]; int vi = red_i[ub * 33];
      #pragma unroll
      for (int s = 1; s < 32; ++s) {
        float v2 = red_v[ub * 33 + s];
        int   i2 = red_i[ub * 33 + s];
        if (v2 > v || (v2 == v && i2 < vi)) { v = v2; vi = i2; }
      }
      out[(b0 + ub) * TLEN + (TLEN - 1)] = vi;
    }
  }
}

extern "C" void kernel_launch(void* const* d_in, const int* in_sizes, int n_in,
                              void* d_out, int out_size, void* d_ws, size_t ws_size,
                              hipStream_t stream) {
  (void)in_sizes; (void)n_in; (void)out_size; (void)ws_size;
  const float* xc  = (const float*)d_in[0];
  const float* xw  = (const float*)d_in[1];
  const float* W   = (const float*)d_in[2];
  const float* U   = (const float*)d_in[3];
  const float* b   = (const float*)d_in[4];
  const float* Wsm = (const float*)d_in[5];
  const float* bs  = (const float*)d_in[6];
  int*   out = (int*)d_out;
  float* ws  = (float*)d_ws;

  hipLaunchKernelGGL(setup_kernel, dim3(64), dim3(256), 0, stream, W, b, ws);

  void* args[] = { (void*)&xc, (void*)&xw, (void*)&W, (void*)&U, (void*)&b,
                   (void*)&Wsm, (void*)&bs, (void*)&out, (void*)&ws };
  hipLaunchCooperativeKernel((const void*)lstm_main, dim3(NBLK), dim3(NTHR),
                             args, 0, stream);
}